// Round 7
// baseline (127.072 us; speedup 1.0000x reference)
//
#include <hip/hip_runtime.h>

// Conv2D 3x3 stride-1 pad-1, C_IN=C_OUT=16, H=W=1024, fp32 in/out.
// Fused implicit-GEMM. v7: 4-deep rolling pipeline, 2-tile-ahead prefetch.
// (Resubmission — round 6 failed on container acquisition, not the kernel.)
//  - r5 post-mortem: raw barriers (no vmcnt drain) gave best-ever (~39us),
//    but read duty still ~60%: with NT=2, once tile-B's prefetch lands the
//    block issues no reads for ~40% of its life, and all 512 phase-locked
//    blocks go read-dead together. Fill kernel proves 6.5 TB/s under
//    CONTINUOUS demand; we need reads outstanding in (nearly) every phase.
//  - v7: TW=64 (byte-clean staging), TH=8, NT=4 tiles/block; grid 16x32 =
//    512 blocks = 2/CU. LDS double-buffer 2x21120B + 5120B weights = 47.4KB.
//    Per iter t: C(t); issue L(t+2)->regs; W(t+1)->other half; raw barrier.
//    Loads in flight during compute, pack AND barrier of every iter except
//    the last compute -> read-dead ~1/8 of lifetime (was ~1/2).
//  - reg ping-pong pA/pB (halo lanes alias scalars into the same float4
//    set); static indexing via explicitly unrolled iter sequence.
//  - barrier = lgkmcnt(0)-only + s_barrier (+sched_barrier fences); global
//    stores never waited. 1 barrier/tile (r2 schedule, proven WAR-safe:
//    the lgkmcnt(0) drain also retires ds_reads, so C(t-1)'s reads are
//    complete before any wave starts W(t+1) into that half).
//  - weights -> bf16 LDS table [t][m][8]; input tile [row][col][cin16] w/
//    16B-chunk XOR swizzle phys = c ^ ((c>>3)&7); 5x K=32
//    mfma_f32_16x16x32_bf16 per output row; v_cvt_pk_bf16_f32 packing.

#define HH 1024
#define WW 1024
#define CIN 16
#define COUT 16
#define TW 64
#define TH 8
#define NT 4                   // vertical tiles per block
#define LROWS (TH + 2)         // 10
#define LCOLS (TW + 2)         // 66
#define PIX 16                 // shorts per pixel (32B = 2 chunks)
#define NPIX (LROWS * LCOLS)   // 660
#define SMHALF (NPIX * PIX)    // 10560 shorts = 21120 B per buffer

typedef short v8s __attribute__((ext_vector_type(8)));
typedef float v4f __attribute__((ext_vector_type(4)));
typedef unsigned int u32;

__device__ __forceinline__ unsigned short f32_bf16(float f) {
    union { float f; u32 u; } v;
    v.f = f;
    u32 u = v.u;
    u += 0x7fffu + ((u >> 16) & 1u);  // RNE
    return (unsigned short)(u >> 16);
}

// packed {bf16(hi)<<16 | bf16(lo)}, hardware RNE
__device__ __forceinline__ u32 cvt_pk_bf16(float lo, float hi) {
    u32 r;
    asm("v_cvt_pk_bf16_f32 %0, %1, %2" : "=v"(r) : "v"(lo), "v"(hi));
    return r;
}

__device__ __forceinline__ int swz(int c) { return c ^ ((c >> 3) & 7); }

// Workgroup barrier WITHOUT the vmcnt(0) store/load drain __syncthreads adds.
__device__ __forceinline__ void wave_barrier() {
    __builtin_amdgcn_sched_barrier(0);
    asm volatile("s_waitcnt lgkmcnt(0)" ::: "memory");
    __builtin_amdgcn_sched_barrier(0);
    __builtin_amdgcn_s_barrier();
    __builtin_amdgcn_sched_barrier(0);
}

__global__ __launch_bounds__(256, 2)
void conv3x3_fused(const float* __restrict__ x,
                   const float* __restrict__ wgt,
                   const float* __restrict__ bias,
                   float* __restrict__ out) {
    __shared__ __align__(16) unsigned short sm[2 * SMHALF];   // 42240 B
    __shared__ __align__(16) unsigned short wsm[20 * 16 * 8]; // 5120 B

    const int tid = threadIdx.x;
    const int lane = tid & 63;
    const int wave = tid >> 6;
    const int h0blk = blockIdx.y * (TH * NT);
    const int w0 = blockIdx.x * TW;

    // ---- weights: coalesced global -> bf16 LDS table [t][m][8] ----
    // wgt linear e = m*144 + c*9 + kh*3 + kw  (c = half*8 + j)
    if (tid < 32) ((uint4*)(wsm + 18 * 16 * 8))[tid] = make_uint4(0u, 0u, 0u, 0u);
    #pragma unroll
    for (int s = 0; s < 9; ++s) {
        const int e = s * 256 + tid;   // 0..2303
        const int m = e / 144;
        const int rem = e - m * 144;
        const int c = rem / 9;
        const int r9 = rem - c * 9;    // kh*3 + kw
        const int t = r9 * 2 + (c >> 3);
        wsm[(t * 16 + m) * 8 + (c & 7)] = f32_bf16(wgt[e]);
    }

    // ---- staging: body tasks 0..159 (r = tid>>4 in 0..9, 4-px group
    //      j = tid&15); halo tasks 160..179 (r = (tid-160)>>1, side = &1).
    //      Halo lanes alias their 16 scalars into f4[0..3] components. ----
    auto load_tile = [&](int t, float4* f4) {
        const int h0 = h0blk + t * TH;
        if (tid < 160) {
            const int r = tid >> 4;
            const int j = tid & 15;
            const int gh = h0 - 1 + r;
            if ((unsigned)gh < (unsigned)HH) {
                const float4* src = (const float4*)(x + (size_t)gh * WW + w0) + j;
                #pragma unroll
                for (int c = 0; c < CIN; ++c)
                    f4[c] = src[(size_t)c * (HH * WW / 4)];
            } else {
                #pragma unroll
                for (int c = 0; c < CIN; ++c)
                    f4[c] = make_float4(0.f, 0.f, 0.f, 0.f);
            }
        } else if (tid < 180) {
            float* f = (float*)f4;
            const int h = tid - 160;
            const int r = h >> 1;
            const int side = h & 1;
            const int gh = h0 - 1 + r;
            const int gw = side ? (w0 + TW) : (w0 - 1);
            if ((unsigned)gh < (unsigned)HH && (unsigned)gw < (unsigned)WW) {
                const float* src = x + (size_t)gh * WW + gw;
                #pragma unroll
                for (int c = 0; c < CIN; ++c) f[c] = src[(size_t)c * (HH * WW)];
            } else {
                #pragma unroll
                for (int c = 0; c < CIN; ++c) f[c] = 0.f;
            }
        }
    };
    auto write_tile = [&](int t, const float4* f4) {
        unsigned short* smb = sm + (t & 1) * SMHALF;
        if (tid < 160) {
            const int r = tid >> 4;
            const int j = tid & 15;
            const int pbase = r * LCOLS + 1 + 4 * j;   // first of 4 pixels
            #pragma unroll
            for (int k = 0; k < 4; ++k) {
                u32 pk[8];
                #pragma unroll
                for (int i = 0; i < 8; ++i) {
                    const float lo = ((const float*)&f4[2 * i])[k];
                    const float hi = ((const float*)&f4[2 * i + 1])[k];
                    pk[i] = cvt_pk_bf16(lo, hi);
                }
                #pragma unroll
                for (int half = 0; half < 2; ++half) {
                    const int cc = 2 * pbase + 2 * k + half;
                    *(uint4*)(smb + swz(cc) * 8) = *(uint4*)&pk[half * 4];
                }
            }
        } else if (tid < 180) {
            const float* f = (const float*)f4;
            const int h = tid - 160;
            const int r = h >> 1;
            const int side = h & 1;
            const int p = r * LCOLS + (side ? (LCOLS - 1) : 0);
            u32 pk[8];
            #pragma unroll
            for (int i = 0; i < 8; ++i)
                pk[i] = cvt_pk_bf16(f[2 * i], f[2 * i + 1]);
            #pragma unroll
            for (int half = 0; half < 2; ++half) {
                const int cc = 2 * p + half;
                *(uint4*)(smb + swz(cc) * 8) = *(uint4*)&pk[half * 4];
            }
        }
    };

    const int m = lane & 15;       // c_out row of A == pixel index n of B/D
    const int q = lane >> 4;       // quad: supplies k = 8q..8q+7 of each MFMA
    const int colbase = wave * 16 + m;

    // ---- B-chunk offsets: chunk t = 4g+q, t<=17 -> (kh,kw,half) ----
    int Kofs[5];
    #pragma unroll
    for (int g5 = 0; g5 < 5; ++g5) {
        int t = 4 * g5 + q;
        int tt = t > 17 ? 17 : t;      // dead lanes use a harmless valid addr
        int khkw = tt >> 1;
        int kh = khkw / 3;
        int kw = khkw - 3 * kh;
        int half = tt & 1;
        Kofs[g5] = (kh * LCOLS + colbase + kw) * 2 + half;
    }
    float bl[4];
    #pragma unroll
    for (int i = 0; i < 4; ++i) bl[i] = bias[q * 4 + i];

    // ---- prologue: stage tile 0; issue tile-1 loads across the barrier ----
    float4 pA[CIN];
    float4 pB[CIN];
    load_tile(0, pA);
    write_tile(0, pA);
    load_tile(1, pB);
    __builtin_amdgcn_sched_barrier(0);   // don't let loads sink past barrier

    wave_barrier();                      // tile-0 ds_writes visible

    // ---- A fragments from the LDS weight table (slots 18,19 are zero) ----
    v8s a[5];
    #pragma unroll
    for (int g5 = 0; g5 < 5; ++g5) {
        const int t = 4 * g5 + q;     // 0..19
        a[g5] = *(const v8s*)(wsm + (t * 16 + m) * 8);
    }

    // ---- compute: wave = 16-col group, 8 rows ----
    auto compute_tile = [&](int t) {
        const unsigned short* smb = sm + (t & 1) * SMHALF;
        const int h0 = h0blk + t * TH;
        #pragma unroll
        for (int r = 0; r < TH; ++r) {
            v4f acc = {0.f, 0.f, 0.f, 0.f};
            #pragma unroll
            for (int g5 = 0; g5 < 5; ++g5) {
                const int c = r * (LCOLS * 2) + Kofs[g5];  // logical chunk
                v8s b = *(const v8s*)(smb + swz(c) * 8);
                acc = __builtin_amdgcn_mfma_f32_16x16x32_bf16(a[g5], b, acc, 0, 0, 0);
            }
            float* op = out + (size_t)(h0 + r) * WW + (w0 + colbase);
            #pragma unroll
            for (int i = 0; i < 4; ++i)
                op[(size_t)(q * 4 + i) * (HH * WW)] = acc[i] + bl[i];
        }
        __builtin_amdgcn_sched_barrier(0);  // keep phases distinct
    };

    // ---- 4-deep rolling pipeline, one raw barrier per tile ----
    // iter t: C(t) [L(t+1) in flight]; issue L(t+2); W(t+1)->other half; BAR.
    // WAR safety: BAR(end of t-1) guarantees all waves finished C(t-1)
    // (same half as W(t+1)); W(t+1) vs C(t) touch different halves.
    compute_tile(0);
    load_tile(2, pA);                  // pA free since W(0)
    __builtin_amdgcn_sched_barrier(0);
    write_tile(1, pB);                 // waits pB loads (oldest outstanding)
    wave_barrier();

    compute_tile(1);
    load_tile(3, pB);                  // pB free since W(1)
    __builtin_amdgcn_sched_barrier(0);
    write_tile(2, pA);
    wave_barrier();

    compute_tile(2);
    write_tile(3, pB);
    wave_barrier();

    compute_tile(3);
}

extern "C" void kernel_launch(void* const* d_in, const int* in_sizes, int n_in,
                              void* d_out, int out_size, void* d_ws, size_t ws_size,
                              hipStream_t stream) {
    const float* x = (const float*)d_in[0];
    const float* w = (const float*)d_in[1];
    const float* b = (const float*)d_in[2];
    float* out = (float*)d_out;
    dim3 grid(WW / TW, HH / (TH * NT));
    conv3x3_fused<<<grid, dim3(256), 0, stream>>>(x, w, b, out);
}